// Round 1
// 709.805 us; speedup vs baseline: 1.0097x; 1.0097x over previous
//
#include <hip/hip_runtime.h>
#include <hip/hip_bf16.h>

#define NN 10000
#define NE 640000
#define NF 128
#define NH 128
#define NT 128
#define KA 256   // NF + NH
#define LN_EPS 1e-5f

typedef __bf16 bf16x8 __attribute__((ext_vector_type(8)));
typedef float floatx4 __attribute__((ext_vector_type(4)));
typedef float nfloat4 __attribute__((ext_vector_type(4)));

__device__ inline unsigned short f2bf(float f) {
    unsigned int u = __float_as_uint(f);
    u += 0x7FFFu + ((u >> 16) & 1u);   // round-to-nearest-even
    return (unsigned short)(u >> 16);
}

__device__ inline bf16x8 load_frag(const unsigned short* p) {
    uint4 u = *(const uint4*)p;
    return __builtin_bit_cast(bf16x8, u);
}

// ---------------------------------------------------------------------------
// Prologue: pack weights f32 [K][N] -> bf16 MFMA-fragment-major order.
// Fragment f=(ct*nks+ks): 64 lanes x 8 elems contiguous (1KB). Lane l holds
// B[k = ks*32 + (l>>4)*8 + j][n = ct*16 + (l&15)]  -> coalesced load_frag.
// ---------------------------------------------------------------------------
__global__ __launch_bounds__(256) void conv_weights(
    const float* __restrict__ W1a, const float* __restrict__ W1b,
    const float* __restrict__ W2a, const float* __restrict__ W2b,
    unsigned short* __restrict__ wp1a, unsigned short* __restrict__ wp1b,
    unsigned short* __restrict__ wp2a, unsigned short* __restrict__ wp2b)
{
    int tid = blockIdx.x * 256 + threadIdx.x;
    const float* src;
    unsigned short* dst;
    int t, nks;
    if (tid < 4096)        { src = W1a; dst = wp1a; t = tid;         nks = 8; }
    else if (tid < 6144)   { src = W1b; dst = wp1b; t = tid - 4096;  nks = 4; }
    else if (tid < 10240)  { src = W2a; dst = wp2a; t = tid - 6144;  nks = 8; }
    else if (tid < 12288)  { src = W2b; dst = wp2b; t = tid - 10240; nks = 4; }
    else return;

    const int f = t >> 6, l = t & 63;
    const int ct = f / nks, ks = f - ct * nks;
    const int n  = ct * 16 + (l & 15);
    const int k0 = ks * 32 + (l >> 4) * 8;
    unsigned short tmp[8];
#pragma unroll
    for (int j = 0; j < 8; ++j)
        tmp[j] = f2bf(src[(k0 + j) * 128 + n]);
    *(uint4*)&dst[t * 8] = *(const uint4*)tmp;
}

// ---------------------------------------------------------------------------
// Counting sort by target row: hist -> scan -> scatter.
// ---------------------------------------------------------------------------
__global__ __launch_bounds__(256) void hist_kernel(
    const int* __restrict__ row, int* __restrict__ hist)
{
    int e = blockIdx.x * 256 + threadIdx.x;
    if (e < NE) atomicAdd(&hist[row[e]], 1);
}

__global__ __launch_bounds__(256) void scan_kernel(
    const int* __restrict__ hist, int* __restrict__ row_start,
    int* __restrict__ cursor)
{
    __shared__ int partials[256];
    const int t = threadIdx.x;
    const int base = t * 40;                  // 256*40 = 10240 >= NN
    int s = 0;
    for (int i = 0; i < 40; ++i) {
        int b = base + i;
        if (b < NN) s += hist[b];
    }
    partials[t] = s;
    __syncthreads();
    int pre = 0;
    for (int i = 0; i < t; ++i) pre += partials[i];
    int run = pre;
    for (int i = 0; i < 40; ++i) {
        int b = base + i;
        if (b < NN) {
            row_start[b] = run;
            cursor[b] = run;
            run += hist[b];
        }
    }
    if (t == 255) row_start[NN] = NE;
}

__global__ __launch_bounds__(256) void scatter_kernel(
    const int* __restrict__ row, int* __restrict__ cursor,
    int* __restrict__ perm)
{
    int e = blockIdx.x * 256 + threadIdx.x;
    if (e < NE) {
        int p = atomicAdd(&cursor[row[e]], 1);
        perm[p] = e;
    }
}

// ---------------------------------------------------------------------------
// Edge MLP, column-split: block = 64 sorted edges, 4 waves each computing a
// 32-column strip of the output for ALL 64 edges. Weights are read once per
// BLOCK (was once per WAVE -> 4x less L2 weight traffic, the prior latency
// bottleneck). A staged once in LDS as packed MFMA fragments (conflict-free
// ds_read_b128/ds_write_b128). LayerNorm = cross-wave 2-stage reduction.
// f32 reduction buffer aliases the A-frag region with +4*row col rotation.
// b1b moved to node kernel (mean(v+b) = mean(v)+b).
// ---------------------------------------------------------------------------
__global__ __launch_bounds__(256, 3) void edge_mlp_kernel(
    const float* __restrict__ x,
    const int* __restrict__ erow, const int* __restrict__ ecol,
    const float* __restrict__ eattr,
    const int* __restrict__ perm,
    const unsigned short* __restrict__ wp1a, const float* __restrict__ b1a,
    const float* __restrict__ g1, const float* __restrict__ be1,
    const unsigned short* __restrict__ wp1b,
    float* __restrict__ sums)
{
    // 32 A-fragments (mt 0..3, ks 0..7), 1KB each = 32KB.
    // Aliased later as accbuf f32 [64][128] (exactly 32KB).
    __shared__ __align__(16) unsigned short Afrag[16384];
    __shared__ unsigned short Ttile[64][NH + 8];        // 17408 B
    __shared__ float2 partials[4][64];                  // 2048 B
    __shared__ float2 murs[64];                         // 512 B
    __shared__ int rows_s[64];                          // 256 B
    // total 52992 B -> 3 blocks/CU

    const int wave = threadIdx.x >> 6;
    const int lane = threadIdx.x & 63;
    const int lm   = lane & 15;
    const int lq4  = lane >> 4;
    const int e0   = blockIdx.x * 64;

    if (threadIdx.x < 64)
        rows_s[threadIdx.x] = erow[perm[e0 + threadIdx.x]];

    // ---- stage A = [x[col[e]] | edge_attr[e]] as packed bf16 fragments ----
    // wave w stages fragments of rows [w*16, w*16+16): frag f = w*8 + ks.
    {
        const int r = wave * 16 + lm;
        const int e = perm[e0 + r];
        const int scol = ecol[e];
        const nfloat4* xr = (const nfloat4*)(x + (size_t)scol * NF) + lq4 * 2;
        const nfloat4* ar = (const nfloat4*)(eattr + (size_t)e * NH) + lq4 * 2;
        unsigned short* dst = &Afrag[(wave * 8) * 512 + lane * 8];
#pragma unroll
        for (int ks = 0; ks < 8; ++ks) {
            nfloat4 v0, v1;
            if (ks < 4) {
                v0 = xr[ks * 8];
                v1 = xr[ks * 8 + 1];
            } else {
                v0 = __builtin_nontemporal_load(ar + (ks - 4) * 8);
                v1 = __builtin_nontemporal_load(ar + (ks - 4) * 8 + 1);
            }
            uint4 wv;
            wv.x = (unsigned)f2bf(v0.x) | ((unsigned)f2bf(v0.y) << 16);
            wv.y = (unsigned)f2bf(v0.z) | ((unsigned)f2bf(v0.w) << 16);
            wv.z = (unsigned)f2bf(v1.x) | ((unsigned)f2bf(v1.y) << 16);
            wv.w = (unsigned)f2bf(v1.z) | ((unsigned)f2bf(v1.w) << 16);
            *(uint4*)(dst + ks * 512) = wv;
        }
    }

    // preload this wave's GEMM1 B-fragments (2 col-tiles x 8 k-steps);
    // independent of LDS, latency hides under staging + barrier.
    bf16x8 b1f[2][8];
#pragma unroll
    for (int c = 0; c < 2; ++c) {
        const int ct = wave * 2 + c;
#pragma unroll
        for (int ks = 0; ks < 8; ++ks)
            b1f[c][ks] = load_frag(&wp1a[((ct * 8 + ks) * 64 + lane) * 8]);
    }

    __syncthreads();

    // ---- GEMM1: [64 x 256] @ [256 x 32] (this wave's column strip) ----
    floatx4 acc1[4][2];
#pragma unroll
    for (int mt = 0; mt < 4; ++mt) {
        bf16x8 a[8];
#pragma unroll
        for (int ks = 0; ks < 8; ++ks)
            a[ks] = load_frag(&Afrag[(mt * 8 + ks) * 512 + lane * 8]);
#pragma unroll
        for (int c = 0; c < 2; ++c) {
            floatx4 acc = {0.f, 0.f, 0.f, 0.f};
#pragma unroll
            for (int ks = 0; ks < 8; ++ks)
                acc = __builtin_amdgcn_mfma_f32_16x16x32_bf16(a[ks], b1f[c][ks], acc, 0, 0, 0);
            acc1[mt][c] = acc;
        }
    }

    // ---- bias + ReLU + per-row partial (sum, sumsq) over 32 cols ----
    const float bb0 = b1a[(wave * 2 + 0) * 16 + lm];
    const float bb1 = b1a[(wave * 2 + 1) * 16 + lm];
#pragma unroll
    for (int mt = 0; mt < 4; ++mt) {
#pragma unroll
        for (int i = 0; i < 4; ++i) {
            float v0 = fmaxf(acc1[mt][0][i] + bb0, 0.f);
            float v1 = fmaxf(acc1[mt][1][i] + bb1, 0.f);
            acc1[mt][0][i] = v0;
            acc1[mt][1][i] = v1;
            float s = v0 + v1;
            float q = v0 * v0 + v1 * v1;
#pragma unroll
            for (int m = 1; m < 16; m <<= 1) {
                s += __shfl_xor(s, m, 64);
                q += __shfl_xor(q, m, 64);
            }
            if (lm == 0)
                partials[wave][mt * 16 + lq4 * 4 + i] = make_float2(s, q);
        }
    }
    __syncthreads();

    // ---- finalize LN stats per row (cross-wave) ----
    if (threadIdx.x < 64) {
        float s = 0.f, q = 0.f;
#pragma unroll
        for (int w2 = 0; w2 < 4; ++w2) {
            float2 p = partials[w2][threadIdx.x];
            s += p.x; q += p.y;
        }
        float mu = s * (1.f / NH);
        float var = q * (1.f / NH) - mu * mu;
        murs[threadIdx.x] = make_float2(mu, rsqrtf(var + LN_EPS));
    }
    __syncthreads();

    // preload GEMM2 B-fragments (latency hides under LN apply)
    bf16x8 b2f[2][4];
#pragma unroll
    for (int c = 0; c < 2; ++c) {
        const int ct = wave * 2 + c;
#pragma unroll
        for (int ks = 0; ks < 4; ++ks)
            b2f[c][ks] = load_frag(&wp1b[((ct * 4 + ks) * 64 + lane) * 8]);
    }

    // ---- apply LN, write bf16 h1 to Ttile ----
    const float gg0 = g1[(wave * 2 + 0) * 16 + lm];
    const float ee0 = be1[(wave * 2 + 0) * 16 + lm];
    const float gg1 = g1[(wave * 2 + 1) * 16 + lm];
    const float ee1 = be1[(wave * 2 + 1) * 16 + lm];
#pragma unroll
    for (int mt = 0; mt < 4; ++mt) {
#pragma unroll
        for (int i = 0; i < 4; ++i) {
            const int row = mt * 16 + lq4 * 4 + i;
            float2 mr = murs[row];
            float n0 = (acc1[mt][0][i] - mr.x) * mr.y * gg0 + ee0;
            float n1 = (acc1[mt][1][i] - mr.x) * mr.y * gg1 + ee1;
            Ttile[row][(wave * 2 + 0) * 16 + lm] = f2bf(n0);
            Ttile[row][(wave * 2 + 1) * 16 + lm] = f2bf(n1);
        }
    }
    __syncthreads();   // Ttile complete; also fences last Afrag reads

    // ---- GEMM2: [64 x 128] @ [128 x 32] ----
    floatx4 acc2[4][2];
#pragma unroll
    for (int mt = 0; mt < 4; ++mt) {
        bf16x8 a[4];
#pragma unroll
        for (int ks = 0; ks < 4; ++ks)
            a[ks] = load_frag(&Ttile[mt * 16 + lm][ks * 32 + lq4 * 8]);
#pragma unroll
        for (int c = 0; c < 2; ++c) {
            floatx4 acc = {0.f, 0.f, 0.f, 0.f};
#pragma unroll
            for (int ks = 0; ks < 4; ++ks)
                acc = __builtin_amdgcn_mfma_f32_16x16x32_bf16(a[ks], b2f[c][ks], acc, 0, 0, 0);
            acc2[mt][c] = acc;
        }
    }

    // ---- write f32 to rotated accbuf (aliases Afrag; conflict-free) ----
    float* accbuf = (float*)Afrag;
#pragma unroll
    for (int mt = 0; mt < 4; ++mt) {
#pragma unroll
        for (int c = 0; c < 2; ++c) {
            const int col = (wave * 2 + c) * 16 + lm;
#pragma unroll
            for (int i = 0; i < 4; ++i) {
                const int row = mt * 16 + lq4 * 4 + i;
                accbuf[row * 128 + ((col + row * 4) & 127)] = acc2[mt][c][i];
            }
        }
    }
    __syncthreads();

    // ---- segmented reduction over the block's 64 sorted edges ----
    {
        const int t = threadIdx.x;
        const int cc = t & 127;
        const int jb = (t >> 7) * 32;
        float a = 0.f;
        int cur = rows_s[jb];
#pragma unroll 4
        for (int j = jb; j < jb + 32; ++j) {
            a += accbuf[j * 128 + ((cc + j * 4) & 127)];
            int nxt = (j + 1 < jb + 32) ? rows_s[j + 1] : -1;
            if (nxt != cur) {
                atomicAdd(&sums[cur * NH + cc], a);
                a = 0.f;
                cur = nxt;
            }
        }
    }
}

// ---------------------------------------------------------------------------
// Node MLP: A = [x[n] | sums[n]/cnt + b1b (cnt>0)], packed weights.
// ---------------------------------------------------------------------------
__global__ __launch_bounds__(256) void node_mlp_kernel(
    const float* __restrict__ x,
    const float* __restrict__ sums, const int* __restrict__ row_start,
    const float* __restrict__ b1b,
    const unsigned short* __restrict__ wp2a, const float* __restrict__ b2a,
    const float* __restrict__ g2, const float* __restrict__ be2,
    const unsigned short* __restrict__ wp2b, const float* __restrict__ b2b,
    float* __restrict__ out)
{
    __shared__ unsigned short Atile[4][16][KA + 8];
    __shared__ unsigned short Ttile[4][16][NH + 8];

    const int wave = threadIdx.x >> 6;
    const int lane = threadIdx.x & 63;
    const int n0 = blockIdx.x * 64 + wave * 16;

    {
        const int lrow = lane >> 2;
        const int lq   = lane & 3;
        int n = n0 + lrow;
        if (n >= NN) n = NN - 1;
        const int cntn = row_start[n + 1] - row_start[n];
        const float inv  = (cntn > 0) ? (1.f / (float)cntn) : 1.f;
        const float addb = (cntn > 0) ? 1.f : 0.f;
        const float4* xr = (const float4*)(x + n * NF);
        const float4* sr = (const float4*)(sums + n * NH);
        const float4* br = (const float4*)b1b;
        unsigned short* Ar = &Atile[wave][lrow][0];
#pragma unroll
        for (int it = 0; it < 8; ++it) {
            int c4 = lq + it * 4;
            float4 v = xr[c4];
            uint2 w;
            w.x = (unsigned)f2bf(v.x) | ((unsigned)f2bf(v.y) << 16);
            w.y = (unsigned)f2bf(v.z) | ((unsigned)f2bf(v.w) << 16);
            *(uint2*)&Ar[c4 * 4] = w;
            float4 v2 = sr[c4];
            float4 bv = br[c4];
            float a0 = v2.x * inv + addb * bv.x;
            float a1 = v2.y * inv + addb * bv.y;
            float a2 = v2.z * inv + addb * bv.z;
            float a3 = v2.w * inv + addb * bv.w;
            uint2 w2;
            w2.x = (unsigned)f2bf(a0) | ((unsigned)f2bf(a1) << 16);
            w2.y = (unsigned)f2bf(a2) | ((unsigned)f2bf(a3) << 16);
            *(uint2*)&Ar[128 + c4 * 4] = w2;
        }
    }
    __syncthreads();

    const int lm  = lane & 15;
    const int lq4 = lane >> 4;

    bf16x8 a1[8];
#pragma unroll
    for (int ks = 0; ks < 8; ++ks)
        a1[ks] = load_frag(&Atile[wave][lm][ks * 32 + lq4 * 8]);

    floatx4 acc1[8];
#pragma unroll
    for (int ct = 0; ct < 8; ++ct) {
        floatx4 acc = {0.f, 0.f, 0.f, 0.f};
        const unsigned short* wr = wp2a + (ct * 8 * 64 + lane) * 8;
#pragma unroll
        for (int ks = 0; ks < 8; ++ks) {
            bf16x8 b = load_frag(wr + ks * 512);
            acc = __builtin_amdgcn_mfma_f32_16x16x32_bf16(a1[ks], b, acc, 0, 0, 0);
        }
        acc1[ct] = acc;
    }

    float sum_[4] = {0, 0, 0, 0}, sq_[4] = {0, 0, 0, 0};
#pragma unroll
    for (int ct = 0; ct < 8; ++ct) {
        const float bb = b2a[ct * 16 + lm];
#pragma unroll
        for (int i = 0; i < 4; ++i) {
            float v = acc1[ct][i] + bb;
            v = fmaxf(v, 0.f);
            acc1[ct][i] = v;
            sum_[i] += v;
            sq_[i]  += v * v;
        }
    }
#pragma unroll
    for (int m = 1; m < 16; m <<= 1) {
#pragma unroll
        for (int i = 0; i < 4; ++i) {
            sum_[i] += __shfl_xor(sum_[i], m, 64);
            sq_[i]  += __shfl_xor(sq_[i],  m, 64);
        }
    }
    float mu[4], rs[4];
#pragma unroll
    for (int i = 0; i < 4; ++i) {
        mu[i] = sum_[i] * (1.f / NH);
        float var = sq_[i] * (1.f / NH) - mu[i] * mu[i];
        rs[i] = rsqrtf(var + LN_EPS);
    }
#pragma unroll
    for (int ct = 0; ct < 8; ++ct) {
        const int c = ct * 16 + lm;
        const float gg = g2[c], bb = be2[c];
#pragma unroll
        for (int i = 0; i < 4; ++i) {
            float nv = (acc1[ct][i] - mu[i]) * rs[i] * gg + bb;
            Ttile[wave][lq4 * 4 + i][c] = f2bf(nv);
        }
    }
    __syncthreads();

    bf16x8 a2[4];
#pragma unroll
    for (int ks = 0; ks < 4; ++ks)
        a2[ks] = load_frag(&Ttile[wave][lm][ks * 32 + lq4 * 8]);

#pragma unroll
    for (int ct = 0; ct < 8; ++ct) {
        floatx4 acc = {0.f, 0.f, 0.f, 0.f};
        const unsigned short* wr = wp2b + (ct * 4 * 64 + lane) * 8;
#pragma unroll
        for (int ks = 0; ks < 4; ++ks) {
            bf16x8 b = load_frag(wr + ks * 512);
            acc = __builtin_amdgcn_mfma_f32_16x16x32_bf16(a2[ks], b, acc, 0, 0, 0);
        }
        const int c = ct * 16 + lm;
        const float bb = b2b[c];
#pragma unroll
        for (int i = 0; i < 4; ++i) {
            int n = n0 + lq4 * 4 + i;
            if (n < NN) out[n * NT + c] = acc[i] + bb;
        }
    }
}

// ---------------------------------------------------------------------------
// Workspace layout (bytes):
//   [0,          5,120,000)  sums      f32 [10000][128]
//   [5,120,000,  5,160,000)  hist      int [10000]
//   [5,160,000,  5,200,000)  cursor    int [10000]
//   [5,200,000,  5,240,064)  row_start int [10001] (padded)
//   [5,240,064,  7,800,064)  perm      int [640000]
//   [7,800,064,  7,865,600)  wp1a      bf16 frag-packed [64 frags][64 lanes][8]
//   [7,865,600,  7,898,368)  wp1b      bf16 frag-packed [32][64][8]
//   [7,898,368,  7,963,904)  wp2a      bf16 frag-packed [64][64][8]
//   [7,963,904,  7,996,672)  wp2b      bf16 frag-packed [32][64][8]
// ---------------------------------------------------------------------------
extern "C" void kernel_launch(void* const* d_in, const int* in_sizes, int n_in,
                              void* d_out, int out_size, void* d_ws, size_t ws_size,
                              hipStream_t stream) {
    const float* x     = (const float*)d_in[0];
    const int*   eidx  = (const int*)d_in[1];
    const float* eattr = (const float*)d_in[2];
    const float* W1a = (const float*)d_in[3];
    const float* b1a = (const float*)d_in[4];
    const float* g1  = (const float*)d_in[5];
    const float* be1 = (const float*)d_in[6];
    const float* W1b = (const float*)d_in[7];
    const float* b1b = (const float*)d_in[8];
    const float* W2a = (const float*)d_in[9];
    const float* b2a = (const float*)d_in[10];
    const float* g2  = (const float*)d_in[11];
    const float* be2 = (const float*)d_in[12];
    const float* W2b = (const float*)d_in[13];
    const float* b2b = (const float*)d_in[14];

    char* ws = (char*)d_ws;
    float* sums     = (float*)ws;
    int*   hist     = (int*)(ws + 5120000);
    int*   cursor   = (int*)(ws + 5160000);
    int*   row_start= (int*)(ws + 5200000);
    int*   perm     = (int*)(ws + 5240064);
    unsigned short* wp1a = (unsigned short*)(ws + 7800064);
    unsigned short* wp1b = (unsigned short*)(ws + 7865600);
    unsigned short* wp2a = (unsigned short*)(ws + 7898368);
    unsigned short* wp2b = (unsigned short*)(ws + 7963904);

    const int* erow = eidx;
    const int* ecol = eidx + NE;

    (void)hipMemsetAsync(ws, 0, 5160000, stream);   // zero sums + hist
    conv_weights<<<48, 256, 0, stream>>>(W1a, W1b, W2a, W2b, wp1a, wp1b, wp2a, wp2b);
    hist_kernel<<<(NE + 255) / 256, 256, 0, stream>>>(erow, hist);
    scan_kernel<<<1, 256, 0, stream>>>(hist, row_start, cursor);
    scatter_kernel<<<(NE + 255) / 256, 256, 0, stream>>>(erow, cursor, perm);
    edge_mlp_kernel<<<NE / 64, 256, 0, stream>>>(x, erow, ecol, eattr, perm,
                                                 wp1a, b1a, g1, be1, wp1b, sums);
    node_mlp_kernel<<<(NN + 63) / 64, 256, 0, stream>>>(x, sums, row_start, b1b,
                                                        wp2a, b2a, g2, be2, wp2b, b2b,
                                                        (float*)d_out);
}